// Round 5
// baseline (3099.469 us; speedup 1.0000x reference)
//
#include <hip/hip_runtime.h>
#include <cstddef>
#include <cstdint>

typedef _Float16 half8  __attribute__((ext_vector_type(8)));
typedef _Float16 half4v __attribute__((ext_vector_type(4)));
typedef float    floatx4 __attribute__((ext_vector_type(4)));
typedef unsigned long long u64;

#define NB 51                       // blocks per node, grid = 5*NB = 255
#define SW(row) (((row)&7)*8)       // LDS xor-swizzle (8-half granules)

#define AGENT_LD(p)    __hip_atomic_load((p), __ATOMIC_RELAXED, __HIP_MEMORY_SCOPE_AGENT)
#define AGENT_ST(p,v)  __hip_atomic_store((p), (v), __ATOMIC_RELAXED, __HIP_MEMORY_SCOPE_AGENT)

// ---- ws layout (bytes) ----
#define HPRE_OFF 0u                 // 8192*256 f32
#define SUM_OFF  8388608u           // 512 f32
#define FLAG_OFF 8390656u           // 256 int
#define CONS_OFF 8391680u           // 256 int
#define SG_OFF   8392704u           // 2*5*8192*64 f16 = 10485760
#define PACK_OFF 18878464u
#define W1P_HALFS 163840
#define W2P_HALFS 327680
#define W3P_HALFS 81920
#define WS_NEEDED 20189184u

// ---- dynamic smem layout for scan (bytes) ----
// Sp  [2][176][64] f16 = 45056
// H1  [64][256] f16    = 32768   (chunk buffer)
// H2  [64][256] f16    = 32768
// xls [2][176] f32     = 1408
// cns [1088] f32       = 4352
#define SMEM_BYTES 116352

__device__ __forceinline__ float fast_tanh(float v) {
    v = fminf(fmaxf(v, -15.f), 15.f);
    float a = exp2f(v * 2.88539008177793f);   // e^{2v}
    return (a - 1.f) / (a + 1.f);
}

// ---------------- pack: f32 weights -> f16 MFMA A-fragment order ----------------
// A-frag 16x16x32: lane holds A[m = mt*16 + (lane&15)][k = kk*32 + (lane>>4)*8 + j]
__global__ __launch_bounds__(256) void pack_kernel(
    const float* __restrict__ W1, const float* __restrict__ W2,
    const float* __restrict__ W3, const float* __restrict__ Wo1,
    _Float16* __restrict__ w1p, _Float16* __restrict__ w2p,
    _Float16* __restrict__ w3p, _Float16* __restrict__ wo1p,
    float* __restrict__ sums, int* __restrict__ flags, int* __restrict__ cons)
{
    int id = blockIdx.x * 256 + threadIdx.x;
    if (id < 512) sums[id] = 0.f;
    if (id < 256) { flags[id] = 0; cons[id] = 0; }
    int f = id >> 6;
    int lane = id & 63;
    int q = lane >> 4, cl = lane & 15;
    if (f < 320) {                           // W1 state rows: frag (n*16+mt)*4+kk
        int kk = f & 3, mt = (f >> 2) & 15, n = f >> 6;
        #pragma unroll
        for (int j = 0; j < 8; j++)
            w1p[(size_t)f*512 + lane*8 + j] =
                (_Float16)W1[(size_t)(n*130 + 2 + kk*32 + q*8 + j)*256 + mt*16 + cl];
    } else if (f < 960) {                    // W2: frag (n*16+mt)*8+kk
        int g = f - 320;
        int kk = g & 7, mt = (g >> 3) & 15, n = g >> 7;
        #pragma unroll
        for (int j = 0; j < 8; j++)
            w2p[(size_t)g*512 + lane*8 + j] =
                (_Float16)W2[(size_t)(n*256 + kk*32 + q*8 + j)*256 + mt*16 + cl];
    } else if (f < 1120) {                   // W3: frag (n*4+mt)*8+kk
        int g = f - 960;
        int kk = g & 7, mt = (g >> 3) & 3, n = g >> 5;
        #pragma unroll
        for (int j = 0; j < 8; j++)
            w3p[(size_t)g*512 + lane*8 + j] =
                (_Float16)W3[(size_t)(n*256 + kk*32 + q*8 + j)*64 + mt*16 + cl];
    } else if (f < 1280) {                   // Wo1 state rows: frag mt*10+kk
        int g = f - 1120;
        int kk = g % 10, mt = g / 10;
        #pragma unroll
        for (int j = 0; j < 8; j++)
            wo1p[(size_t)g*512 + lane*8 + j] =
                (_Float16)Wo1[(size_t)(5 + kk*32 + q*8 + j)*256 + mt*16 + cl];
    }
}

// ---------------- scan: node-specialized persistent blocks ----------------
// Cross-block coherence: ALL Sg/flag/cons traffic uses agent-scope (sc1)
// atomics -> served at the shared LLC, no L1/L2 staleness, NO fences needed.
template<int NT>
__device__ __attribute__((always_inline)) void scan_impl(
    const float* __restrict__ x, const float* __restrict__ W1,
    const float* __restrict__ b1, const float* __restrict__ b2, const float* __restrict__ b3,
    const _Float16* __restrict__ w1p, const _Float16* __restrict__ w2p,
    const _Float16* __restrict__ w3p,
    _Float16* __restrict__ Sg, int* flags, int* cons,
    char* smem, int n, int idx, int r0)
{
    constexpr int BB  = NT * 16;
    constexpr int NCH = 3;
    _Float16* Sp  = (_Float16*)smem;                 // [2][176][64] swizzled
    _Float16* H1  = (_Float16*)(smem + 45056);       // [64][256] swizzled (chunk)
    _Float16* H2  = (_Float16*)(smem + 77824);
    float*    xls = (float*)(smem + 110592);         // [2][176]
    float*    cns = (float*)(smem + 112000);         // 1088 floats

    const int tid = threadIdx.x, w = tid >> 6, lane = tid & 63;
    const int quad = lane >> 4, cl = lane & 15;
    const int P0t[5] = {3,0,0,1,2}, P1t[5] = {4,4,1,2,3};
    const int p0 = P0t[n], p1 = P1t[n];
    const int myix = n*NB + idx, f0ix = p0*NB + idx, f1ix = p1*NB + idx;
    const int mt3 = w & 3, half = w >> 2;
    const int mtg = w & 3, rh = w >> 2;      // L2 roles: feat-group, row-half

    // ---- resident weight fragments (loaded once) ----
    half8 w1f[2][4], w2f[4][8], w3f[8];
    #pragma unroll
    for (int i = 0; i < 2; i++) {
        int mt = 2*w + i;
        #pragma unroll
        for (int kk = 0; kk < 4; kk++)
            w1f[i][kk] = *(const half8*)(w1p + (size_t)((n*16 + mt)*4 + kk)*512 + lane*8);
    }
    #pragma unroll
    for (int i = 0; i < 4; i++) {
        int mt = mtg*4 + i;
        #pragma unroll
        for (int kk = 0; kk < 8; kk++)
            w2f[i][kk] = *(const half8*)(w2p + (size_t)((n*16 + mt)*8 + kk)*512 + lane*8);
    }
    #pragma unroll
    for (int kk = 0; kk < 8; kk++)
        w3f[kk] = *(const half8*)(w3p + (size_t)((n*4 + mt3)*8 + kk)*512 + lane*8);

    // ---- stage per-node constants ----
    for (int i = tid; i < 1088; i += 512) {
        float v;
        if      (i < 256) v = b1[n*256 + i];
        else if (i < 512) v = b2[n*256 + i - 256];
        else if (i < 576) v = b3[n*64  + i - 512];
        else { int j = i - 576; v = W1[(size_t)(n*130 + (j>>8))*256 + (j & 255)]; }
        cns[i] = v;
    }

    auto stage_rows = [&](int first_row, int R, int buf) {
        int tot = 2*R*8;
        for (int i = tid; i < tot; i += 512) {
            int pp = i >= R*8;
            int rem = i - pp*R*8;
            int rl = rem >> 3, g8 = rem & 7;
            int grow = first_row + rl;
            u64* src = (u64*)(Sg + ((size_t)((buf*5 + (pp ? p1 : p0))*8192 + r0 + grow))*64 + g8*8);
            u64 lo = AGENT_LD(src);
            u64 hi = AGENT_LD(src + 1);
            union { u64 q[2]; half8 h; } u; u.q[0] = lo; u.q[1] = hi;
            *(half8*)&Sp[pp*11264 + grow*64 + ((g8*8) ^ SW(grow))] = u.h;
        }
    };

    for (int t = 0; t < 128; t++) {
        // ---- phase 0: neighbor sync (no fences; sc1 traffic only) ----
        if (t > 0 && tid < 2) {
            int* fp = &flags[tid ? f1ix : f0ix];
            while (AGENT_LD(fp) < t) __builtin_amdgcn_s_sleep(2);
        }
        if (t >= 2 && tid == 2) {
            int need = 2*(t-1);
            while (AGENT_LD(&cons[myix]) < need) __builtin_amdgcn_s_sleep(2);
        }
        __syncthreads();

        // ---- phase 1: stage chunk-0 parent rows + x_t ----
        if (t > 0) stage_rows(0, 64, (t-1) & 1);
        for (int i = tid; i < 2*BB; i += 512) {
            int pp = i >= BB; int rl = i - pp*BB;
            xls[pp*176 + rl] = x[(size_t)(r0 + rl)*640 + (pp ? p1 : p0)*128 + t];
        }
        __syncthreads();

        // ---- phase 2: chunks of 4 row-tiles: L1 -> L2 -> L3 ----
        #pragma unroll
        for (int c = 0; c < NCH; c++) {
            const int rem_nt = NT - c*4;
            const int cnt = rem_nt < 4 ? rem_nt : 4;
            const int base16 = c*64;

            // stage next chunk's parent rows (overlapped with L1 compute)
            if (t > 0 && c + 1 < NCH) {
                int fr = (c+1)*64;
                int R = BB - fr; if (R > 64) R = 64;
                stage_rows(fr, R, (t-1) & 1);
            }

            // ---- L1: i=2 feat-tiles (32 feats/wave), all row-tiles ----
            {
                floatx4 a1[2][4];
                #pragma unroll
                for (int i = 0; i < 2; i++) {
                    int fb = (2*w + i)*16 + quad*4;
                    floatx4 bv = *(const floatx4*)&cns[fb];
                    floatx4 u0 = *(const floatx4*)&cns[576 + fb];
                    floatx4 u1 = *(const floatx4*)&cns[832 + fb];
                    #pragma unroll
                    for (int j = 0; j < 4; j++) if (j < cnt) {
                        int rb = base16 + j*16 + cl;
                        float xa = xls[rb], xc = xls[176 + rb];
                        a1[i][j] = bv + u0*xa + u1*xc;
                    }
                }
                if (t > 0) {
                    #pragma unroll
                    for (int kk = 0; kk < 4; kk++)
                        #pragma unroll
                        for (int j = 0; j < 4; j++) if (j < cnt) {
                            half8 bf = *(const half8*)&Sp[(kk>>1)*11264 + (base16 + j*16 + cl)*64
                                                          + (((kk&1)*32 + quad*8) ^ SW(cl))];
                            a1[0][j] = __builtin_amdgcn_mfma_f32_16x16x32_f16(w1f[0][kk], bf, a1[0][j], 0,0,0);
                            a1[1][j] = __builtin_amdgcn_mfma_f32_16x16x32_f16(w1f[1][kk], bf, a1[1][j], 0,0,0);
                        }
                }
                #pragma unroll
                for (int i = 0; i < 2; i++) {
                    int fb = (2*w + i)*16 + quad*4;
                    #pragma unroll
                    for (int j = 0; j < 4; j++) if (j < cnt) {
                        int rl = j*16 + cl;
                        half4v pk;
                        #pragma unroll
                        for (int r = 0; r < 4; r++)
                            pk[r] = (_Float16)fmaxf(a1[i][j][r], 0.f);
                        *(half4v*)&H1[rl*256 + (fb ^ SW(cl))] = pk;
                    }
                }
            }
            __syncthreads();   // L1 done (also next-chunk staging drained)

            // signal producers once staging of the LAST chunk has drained
            if (c == NCH-2 && t > 0 && tid < 2)
                __hip_atomic_fetch_add(&cons[tid ? f1ix : f0ix], 1,
                                       __ATOMIC_RELAXED, __HIP_MEMORY_SCOPE_AGENT);

            // ---- L2: 256 -> 256, i=4 feat-tiles (64 feats/wave), row-half split ----
            {
                floatx4 a2[4][2];
                #pragma unroll
                for (int i = 0; i < 4; i++) {
                    int fb = (mtg*4 + i)*16 + quad*4;
                    floatx4 bv = *(const floatx4*)&cns[256 + fb];
                    #pragma unroll
                    for (int jj = 0; jj < 2; jj++) a2[i][jj] = bv;
                }
                #pragma unroll
                for (int kk = 0; kk < 8; kk++)
                    #pragma unroll
                    for (int jj = 0; jj < 2; jj++) {
                        int j = rh*2 + jj;
                        if (j < cnt) {
                            half8 bf = *(const half8*)&H1[(j*16 + cl)*256 + ((kk*32 + quad*8) ^ SW(cl))];
                            #pragma unroll
                            for (int i = 0; i < 4; i++)
                                a2[i][jj] = __builtin_amdgcn_mfma_f32_16x16x32_f16(w2f[i][kk], bf, a2[i][jj], 0,0,0);
                        }
                    }
                #pragma unroll
                for (int i = 0; i < 4; i++) {
                    int fb = (mtg*4 + i)*16 + quad*4;
                    #pragma unroll
                    for (int jj = 0; jj < 2; jj++) {
                        int j = rh*2 + jj;
                        if (j < cnt) {
                            int rl = j*16 + cl;
                            half4v pk;
                            #pragma unroll
                            for (int r = 0; r < 4; r++)
                                pk[r] = (_Float16)fmaxf(a2[i][jj][r], 0.f);
                            *(half4v*)&H2[rl*256 + (fb ^ SW(cl))] = pk;
                        }
                    }
                }
            }
            __syncthreads();   // L2 done

            // ---- L3: 256 -> 64, tanh, state -> global (agent-scope store) ----
            {
                int f3 = mt3*16 + quad*4;
                floatx4 bv = *(const floatx4*)&cns[512 + f3];
                floatx4 a3[2];
                #pragma unroll
                for (int jj = 0; jj < 2; jj++) a3[jj] = bv;
                #pragma unroll
                for (int kk = 0; kk < 8; kk++)
                    #pragma unroll
                    for (int jj = 0; jj < 2; jj++) {
                        int j = half*2 + jj;
                        if (j < cnt) {
                            half8 bf = *(const half8*)&H2[(j*16 + cl)*256 + ((kk*32 + quad*8) ^ SW(cl))];
                            a3[jj] = __builtin_amdgcn_mfma_f32_16x16x32_f16(w3f[kk], bf, a3[jj], 0,0,0);
                        }
                    }
                #pragma unroll
                for (int jj = 0; jj < 2; jj++) {
                    int j = half*2 + jj;
                    if (j < cnt) {
                        int grow = r0 + base16 + j*16 + cl;
                        union { _Float16 hh[4]; u64 q; } pk;
                        #pragma unroll
                        for (int r = 0; r < 4; r++) pk.hh[r] = (_Float16)fast_tanh(a3[jj][r]);
                        AGENT_ST((u64*)(Sg + ((size_t)(((t&1)*5 + n)*8192 + grow))*64 + f3), pk.q);
                    }
                }
            }
            // no barrier: next chunk's L1 writes H1 (disjoint from H2 readers)
        }

        // ---- publish: barrier drains vmcnt(0) for all waves, then flag ----
        __syncthreads();
        if (tid == 0)
            AGENT_ST(&flags[myix], t+1);
    }
}

__global__ __launch_bounds__(512, 2) void scan_kernel(
    const float* __restrict__ x, const float* __restrict__ W1,
    const float* __restrict__ b1, const float* __restrict__ b2, const float* __restrict__ b3,
    const _Float16* __restrict__ w1p, const _Float16* __restrict__ w2p,
    const _Float16* __restrict__ w3p,
    _Float16* __restrict__ Sg, int* flags, int* cons)
{
    extern __shared__ char smem[];
    int b = blockIdx.x;
    int n = b / NB, idx = b % NB;
    int r0 = idx < 2 ? idx*176 : 352 + (idx-2)*160;
    if (idx < 2)
        scan_impl<11>(x, W1, b1, b2, b3, w1p, w2p, w3p, Sg, flags, cons, smem, n, idx, r0);
    else
        scan_impl<10>(x, W1, b1, b2, b3, w1p, w2p, w3p, Sg, flags, cons, smem, n, idx, r0);
}

// ---------------- hpre: relu([x_127, states] @ Wo1 + bo1) ----------------
__global__ __launch_bounds__(512) void hpre_kernel(
    const float* __restrict__ x, const float* __restrict__ Wo1, const float* __restrict__ bo1,
    const _Float16* __restrict__ wo1p, const _Float16* __restrict__ Sg,
    float* __restrict__ hpre)
{
    __shared__ float x5[640];     // [5][128]
    __shared__ float wxo[1280];   // Wo1 rows 0..4
    __shared__ float bo1c[256];
    int tid = threadIdx.x, w = tid >> 6, lane = tid & 63;
    int quad = lane >> 4, cl = lane & 15;
    int r0h = blockIdx.x * 128;

    for (int i = tid; i < 640; i += 512)
        x5[i] = x[(size_t)(r0h + (i & 127))*640 + (i >> 7)*128 + 127];
    for (int i = tid; i < 1280; i += 512) wxo[i] = Wo1[i];
    if (tid < 256) bo1c[tid] = bo1[tid];

    half8 of[2][10];
    #pragma unroll
    for (int i = 0; i < 2; i++) {
        int mt = 2*w + i;
        #pragma unroll
        for (int kk = 0; kk < 10; kk++)
            of[i][kk] = *(const half8*)(wo1p + (size_t)(mt*10 + kk)*512 + lane*8);
    }
    __syncthreads();

    floatx4 acc[2][8];
    #pragma unroll
    for (int i = 0; i < 2; i++) {
        int fb = (2*w + i)*16 + quad*4;
        floatx4 bv = *(const floatx4*)&bo1c[fb];
        #pragma unroll
        for (int nt = 0; nt < 8; nt++) {
            floatx4 a = bv;
            #pragma unroll
            for (int p = 0; p < 5; p++) {
                floatx4 wv = *(const floatx4*)&wxo[p*256 + fb];
                float xv = x5[p*128 + nt*16 + cl];
                a += wv * xv;
            }
            acc[i][nt] = a;
        }
    }
    #pragma unroll
    for (int kk = 0; kk < 10; kk++) {
        int nd = kk >> 1;
        #pragma unroll
        for (int nt = 0; nt < 8; nt++) {
            const _Float16* sp = Sg + ((size_t)((5 + nd)*8192 + r0h + nt*16 + cl))*64
                                    + (kk & 1)*32 + quad*8;   // buf 1 = state(127)
            half8 bf = *(const half8*)sp;
            acc[0][nt] = __builtin_amdgcn_mfma_f32_16x16x32_f16(of[0][kk], bf, acc[0][nt], 0,0,0);
            acc[1][nt] = __builtin_amdgcn_mfma_f32_16x16x32_f16(of[1][kk], bf, acc[1][nt], 0,0,0);
        }
    }
    #pragma unroll
    for (int i = 0; i < 2; i++) {
        int fb = (2*w + i)*16 + quad*4;
        #pragma unroll
        for (int nt = 0; nt < 8; nt++) {
            floatx4 v = acc[i][nt];
            #pragma unroll
            for (int r = 0; r < 4; r++) v[r] = fmaxf(v[r], 0.f);
            *(floatx4*)&hpre[(size_t)(r0h + nt*16 + cl)*256 + fb] = v;
        }
    }
}

// ---------------- BN stats ----------------
__global__ __launch_bounds__(256) void bnstats_kernel(const float* __restrict__ hpre,
                                                      float* __restrict__ sums)
{
    int col = threadIdx.x;
    int r0 = blockIdx.x * 128;
    float s = 0.f, s2 = 0.f;
    for (int r = 0; r < 128; r++) {
        float v = hpre[(size_t)(r0 + r)*256 + col];
        s += v; s2 += v*v;
    }
    atomicAdd(&sums[col], s);
    atomicAdd(&sums[256 + col], s2);
}

// ---------------- normalize + Wo2 + softmax ----------------
__global__ __launch_bounds__(256) void head_kernel(
    const float* __restrict__ hpre, const float* __restrict__ sums,
    const float* __restrict__ gamma, const float* __restrict__ beta,
    const float* __restrict__ Wo2, const float* __restrict__ bo2,
    float* __restrict__ out)
{
    int row  = blockIdx.x * 4 + (threadIdx.x >> 6);
    int lane = threadIdx.x & 63;
    floatx4 h  = *(const floatx4*)&hpre[(size_t)row*256 + lane*4];
    floatx4 sm = *(const floatx4*)&sums[lane*4];
    floatx4 sq = *(const floatx4*)&sums[256 + lane*4];
    floatx4 g  = *(const floatx4*)&gamma[lane*4];
    floatx4 bb = *(const floatx4*)&beta[lane*4];
    float acc[7] = {0.f,0.f,0.f,0.f,0.f,0.f,0.f};
    #pragma unroll
    for (int e = 0; e < 4; e++) {
        float mu  = sm[e] * (1.f/8192.f);
        float var = sq[e] * (1.f/8192.f) - mu*mu;
        float hn  = (h[e] - mu) * rsqrtf(var + 1e-5f) * g[e] + bb[e];
        int colg = lane*4 + e;
        #pragma unroll
        for (int j = 0; j < 7; j++) acc[j] += hn * Wo2[colg*7 + j];
    }
    #pragma unroll
    for (int off = 1; off < 64; off <<= 1) {
        #pragma unroll
        for (int j = 0; j < 7; j++) acc[j] += __shfl_xor(acc[j], off, 64);
    }
    float z[7], m = -1e30f;
    #pragma unroll
    for (int j = 0; j < 7; j++) { z[j] = acc[j] + bo2[j]; m = fmaxf(m, z[j]); }
    float se = 0.f;
    #pragma unroll
    for (int j = 0; j < 7; j++) { z[j] = expf(z[j] - m); se += z[j]; }
    if (lane < 7) out[(size_t)row*7 + lane] = z[lane] / se;
}

extern "C" void kernel_launch(void* const* d_in, const int* in_sizes, int n_in,
                              void* d_out, int out_size, void* d_ws, size_t ws_size,
                              hipStream_t stream)
{
    const float* x    = (const float*)d_in[0];
    const float* W1   = (const float*)d_in[1];
    const float* b1   = (const float*)d_in[2];
    const float* W2   = (const float*)d_in[3];
    const float* b2   = (const float*)d_in[4];
    const float* W3   = (const float*)d_in[5];
    const float* b3   = (const float*)d_in[6];
    const float* Wo1  = (const float*)d_in[7];
    const float* bo1  = (const float*)d_in[8];
    const float* gamma= (const float*)d_in[9];
    const float* beta = (const float*)d_in[10];
    const float* Wo2  = (const float*)d_in[11];
    const float* bo2  = (const float*)d_in[12];
    float* out = (float*)d_out;

    if (ws_size < WS_NEEDED) return;
    char* ws = (char*)d_ws;
    float*     hpre  = (float*)(ws + HPRE_OFF);
    float*     sums  = (float*)(ws + SUM_OFF);
    int*       flags = (int*)(ws + FLAG_OFF);
    int*       cons  = (int*)(ws + CONS_OFF);
    _Float16*  Sg    = (_Float16*)(ws + SG_OFF);
    _Float16*  w1p   = (_Float16*)(ws + PACK_OFF);
    _Float16*  w2p   = w1p + W1P_HALFS;
    _Float16*  w3p   = w2p + W2P_HALFS;
    _Float16*  wo1p  = w3p + W3P_HALFS;

    hipFuncSetAttribute((const void*)scan_kernel,
                        hipFuncAttributeMaxDynamicSharedMemorySize, SMEM_BYTES);

    pack_kernel<<<320, 256, 0, stream>>>(W1, W2, W3, Wo1, w1p, w2p, w3p, wo1p,
                                         sums, flags, cons);
    scan_kernel<<<5*NB, 512, SMEM_BYTES, stream>>>(x, W1, b1, b2, b3,
                                                   w1p, w2p, w3p, Sg, flags, cons);
    hpre_kernel<<<64, 512, 0, stream>>>(x, Wo1, bo1, wo1p, Sg, hpre);
    bnstats_kernel<<<64, 256, 0, stream>>>(hpre, sums);
    head_kernel<<<2048, 256, 0, stream>>>(hpre, sums, gamma, beta, Wo2, bo2, out);
}

// Round 6
// 2496.792 us; speedup vs baseline: 1.2414x; 1.2414x over previous
//
#include <hip/hip_runtime.h>
#include <cstddef>
#include <cstdint>

typedef _Float16 half8  __attribute__((ext_vector_type(8)));
typedef _Float16 half4v __attribute__((ext_vector_type(4)));
typedef float    floatx4 __attribute__((ext_vector_type(4)));
typedef unsigned long long u64;

#define NB 51                       // blocks per node, grid = 5*NB = 255
#define SW(row) (((row)&7)*8)       // LDS xor-swizzle (8-half granules)

#define AGENT_LD(p)    __hip_atomic_load((p), __ATOMIC_RELAXED, __HIP_MEMORY_SCOPE_AGENT)
#define AGENT_ST(p,v)  __hip_atomic_store((p), (v), __ATOMIC_RELAXED, __HIP_MEMORY_SCOPE_AGENT)

// ---- ws layout (bytes) ----
#define HPRE_OFF 0u                 // 8192*256 f32
#define SUM_OFF  8388608u           // 512 f32
#define FLAG_OFF 8390656u           // 256 int
#define CONS_OFF 8391680u           // 256 int
#define SG_OFF   8392704u           // 2*5*8192*64 f16 = 10485760
#define PACK_OFF 18878464u
#define W1P_HALFS 163840
#define W2P_HALFS 327680
#define W3P_HALFS 81920
#define WS_NEEDED 20189184u

// ---- dynamic smem layout for scan (bytes) ----
// Sp  [2][176][64] f16 = 45056
// H1  [64][256] f16    = 32768   (chunk buffer)
// H2  [64][256] f16    = 32768
// xls [2][176] f32     = 1408
// cns [1088] f32       = 4352
// w3l 32 frags f16     = 32768   (w3 A-fragments, LDS-resident)
#define SMEM_BYTES 149120

__device__ __forceinline__ float fast_tanh(float v) {
    v = fminf(fmaxf(v, -15.f), 15.f);
    float a = exp2f(v * 2.88539008177793f);   // e^{2v}
    return (a - 1.f) / (a + 1.f);
}

// ---------------- pack: f32 weights -> f16 MFMA A-fragment order ----------------
// A-frag 16x16x32: lane holds A[m = mt*16 + (lane&15)][k = kk*32 + (lane>>4)*8 + j]
__global__ __launch_bounds__(256) void pack_kernel(
    const float* __restrict__ W1, const float* __restrict__ W2,
    const float* __restrict__ W3, const float* __restrict__ Wo1,
    _Float16* __restrict__ w1p, _Float16* __restrict__ w2p,
    _Float16* __restrict__ w3p, _Float16* __restrict__ wo1p,
    float* __restrict__ sums, int* __restrict__ flags, int* __restrict__ cons)
{
    int id = blockIdx.x * 256 + threadIdx.x;
    if (id < 512) sums[id] = 0.f;
    if (id < 256) { flags[id] = 0; cons[id] = 0; }
    int f = id >> 6;
    int lane = id & 63;
    int q = lane >> 4, cl = lane & 15;
    if (f < 320) {                           // W1 state rows: frag (n*16+mt)*4+kk
        int kk = f & 3, mt = (f >> 2) & 15, n = f >> 6;
        #pragma unroll
        for (int j = 0; j < 8; j++)
            w1p[(size_t)f*512 + lane*8 + j] =
                (_Float16)W1[(size_t)(n*130 + 2 + kk*32 + q*8 + j)*256 + mt*16 + cl];
    } else if (f < 960) {                    // W2: frag (n*16+mt)*8+kk
        int g = f - 320;
        int kk = g & 7, mt = (g >> 3) & 15, n = g >> 7;
        #pragma unroll
        for (int j = 0; j < 8; j++)
            w2p[(size_t)g*512 + lane*8 + j] =
                (_Float16)W2[(size_t)(n*256 + kk*32 + q*8 + j)*256 + mt*16 + cl];
    } else if (f < 1120) {                   // W3: frag (n*4+mt)*8+kk
        int g = f - 960;
        int kk = g & 7, mt = (g >> 3) & 3, n = g >> 5;
        #pragma unroll
        for (int j = 0; j < 8; j++)
            w3p[(size_t)g*512 + lane*8 + j] =
                (_Float16)W3[(size_t)(n*256 + kk*32 + q*8 + j)*64 + mt*16 + cl];
    } else if (f < 1280) {                   // Wo1 state rows: frag mt*10+kk
        int g = f - 1120;
        int kk = g % 10, mt = g / 10;
        #pragma unroll
        for (int j = 0; j < 8; j++)
            wo1p[(size_t)g*512 + lane*8 + j] =
                (_Float16)Wo1[(size_t)(5 + kk*32 + q*8 + j)*256 + mt*16 + cl];
    }
}

// ---------------- scan: node-specialized persistent blocks ----------------
// Cross-block coherence: ALL Sg/flag/cons traffic uses agent-scope (sc1)
// atomics -> served at the shared LLC, no L1/L2 staleness, NO fences needed.
// Weights: w1 (8 frags) + w2 (32 frags, i=4 reuse) register-resident;
// w3 (32 frags) LDS-resident -> total reg demand ~225 < 256, no remat.
template<int NT>
__device__ __attribute__((always_inline)) void scan_impl(
    const float* __restrict__ x, const float* __restrict__ W1,
    const float* __restrict__ b1, const float* __restrict__ b2, const float* __restrict__ b3,
    const _Float16* __restrict__ w1p, const _Float16* __restrict__ w2p,
    const _Float16* __restrict__ w3p,
    _Float16* __restrict__ Sg, int* flags, int* cons,
    char* smem, int n, int idx, int r0)
{
    constexpr int BB  = NT * 16;
    constexpr int NCH = 3;
    _Float16* Sp  = (_Float16*)smem;                 // [2][176][64] swizzled
    _Float16* H1  = (_Float16*)(smem + 45056);       // [64][256] swizzled (chunk)
    _Float16* H2  = (_Float16*)(smem + 77824);
    float*    xls = (float*)(smem + 110592);         // [2][176]
    float*    cns = (float*)(smem + 112000);         // 1088 floats
    _Float16* w3l = (_Float16*)(smem + 116352);      // 32 w3 A-frags (16384 halfs)

    const int tid = threadIdx.x, w = tid >> 6, lane = tid & 63;
    const int quad = lane >> 4, cl = lane & 15;
    const int P0t[5] = {3,0,0,1,2}, P1t[5] = {4,4,1,2,3};
    const int p0 = P0t[n], p1 = P1t[n];
    const int myix = n*NB + idx, f0ix = p0*NB + idx, f1ix = p1*NB + idx;
    const int mt3 = w & 3, half = w >> 2;
    const int mtg = w & 3, rh = w >> 2;      // L2 roles: feat-group, row-half

    // ---- resident weight fragments (loaded once) ----
    half8 w1f[2][4], w2f[4][8];
    #pragma unroll
    for (int i = 0; i < 2; i++) {
        int mt = 2*w + i;
        #pragma unroll
        for (int kk = 0; kk < 4; kk++)
            w1f[i][kk] = *(const half8*)(w1p + (size_t)((n*16 + mt)*4 + kk)*512 + lane*8);
    }
    #pragma unroll
    for (int i = 0; i < 4; i++) {
        int mt = mtg*4 + i;
        #pragma unroll
        for (int kk = 0; kk < 8; kk++)
            w2f[i][kk] = *(const half8*)(w2p + (size_t)((n*16 + mt)*8 + kk)*512 + lane*8);
    }

    // ---- stage w3 frags into LDS (node-local 32 frags, contiguous) ----
    for (int i = tid; i < 16384; i += 512) w3l[i] = w3p[(size_t)n*16384 + i];

    // ---- stage per-node constants ----
    for (int i = tid; i < 1088; i += 512) {
        float v;
        if      (i < 256) v = b1[n*256 + i];
        else if (i < 512) v = b2[n*256 + i - 256];
        else if (i < 576) v = b3[n*64  + i - 512];
        else { int j = i - 576; v = W1[(size_t)(n*130 + (j>>8))*256 + (j & 255)]; }
        cns[i] = v;
    }

    auto stage_rows = [&](int first_row, int R, int buf) {
        int tot = 2*R*8;
        for (int i = tid; i < tot; i += 512) {
            int pp = i >= R*8;
            int rem = i - pp*R*8;
            int rl = rem >> 3, g8 = rem & 7;
            int grow = first_row + rl;
            u64* src = (u64*)(Sg + ((size_t)((buf*5 + (pp ? p1 : p0))*8192 + r0 + grow))*64 + g8*8);
            u64 lo = AGENT_LD(src);
            u64 hi = AGENT_LD(src + 1);
            union { u64 q[2]; half8 h; } u; u.q[0] = lo; u.q[1] = hi;
            *(half8*)&Sp[pp*11264 + grow*64 + ((g8*8) ^ SW(grow))] = u.h;
        }
    };

    for (int t = 0; t < 128; t++) {
        // ---- phase 0: neighbor sync (no fences; sc1 traffic only) ----
        if (t > 0 && tid < 2) {
            int* fp = &flags[tid ? f1ix : f0ix];
            while (AGENT_LD(fp) < t) __builtin_amdgcn_s_sleep(2);
        }
        if (t >= 2 && tid == 2) {
            int need = 2*(t-1);
            while (AGENT_LD(&cons[myix]) < need) __builtin_amdgcn_s_sleep(2);
        }
        __syncthreads();

        // ---- phase 1: stage chunk-0 parent rows + x_t ----
        if (t > 0) stage_rows(0, 64, (t-1) & 1);
        for (int i = tid; i < 2*BB; i += 512) {
            int pp = i >= BB; int rl = i - pp*BB;
            xls[pp*176 + rl] = x[(size_t)(r0 + rl)*640 + (pp ? p1 : p0)*128 + t];
        }
        __syncthreads();

        // ---- phase 2: chunks of 4 row-tiles: L1 -> L2 -> L3 ----
        #pragma unroll
        for (int c = 0; c < NCH; c++) {
            const int rem_nt = NT - c*4;
            const int cnt = rem_nt < 4 ? rem_nt : 4;
            const int base16 = c*64;

            // stage next chunk's parent rows (overlapped with L1 compute)
            if (t > 0 && c + 1 < NCH) {
                int fr = (c+1)*64;
                int R = BB - fr; if (R > 64) R = 64;
                stage_rows(fr, R, (t-1) & 1);
            }

            // ---- L1: i=2 feat-tiles (32 feats/wave), all row-tiles ----
            {
                floatx4 a1[2][4];
                #pragma unroll
                for (int i = 0; i < 2; i++) {
                    int fb = (2*w + i)*16 + quad*4;
                    floatx4 bv = *(const floatx4*)&cns[fb];
                    floatx4 u0 = *(const floatx4*)&cns[576 + fb];
                    floatx4 u1 = *(const floatx4*)&cns[832 + fb];
                    #pragma unroll
                    for (int j = 0; j < 4; j++) if (j < cnt) {
                        int rb = base16 + j*16 + cl;
                        float xa = xls[rb], xc = xls[176 + rb];
                        a1[i][j] = bv + u0*xa + u1*xc;
                    }
                }
                if (t > 0) {
                    #pragma unroll
                    for (int kk = 0; kk < 4; kk++)
                        #pragma unroll
                        for (int j = 0; j < 4; j++) if (j < cnt) {
                            half8 bf = *(const half8*)&Sp[(kk>>1)*11264 + (base16 + j*16 + cl)*64
                                                          + (((kk&1)*32 + quad*8) ^ SW(cl))];
                            a1[0][j] = __builtin_amdgcn_mfma_f32_16x16x32_f16(w1f[0][kk], bf, a1[0][j], 0,0,0);
                            a1[1][j] = __builtin_amdgcn_mfma_f32_16x16x32_f16(w1f[1][kk], bf, a1[1][j], 0,0,0);
                        }
                }
                #pragma unroll
                for (int i = 0; i < 2; i++) {
                    int fb = (2*w + i)*16 + quad*4;
                    #pragma unroll
                    for (int j = 0; j < 4; j++) if (j < cnt) {
                        int rl = j*16 + cl;
                        half4v pk;
                        #pragma unroll
                        for (int r = 0; r < 4; r++)
                            pk[r] = (_Float16)fmaxf(a1[i][j][r], 0.f);
                        *(half4v*)&H1[rl*256 + (fb ^ SW(cl))] = pk;
                    }
                }
            }
            __syncthreads();   // L1 done (also next-chunk staging drained)

            // signal producers once staging of the LAST chunk has drained
            if (c == NCH-2 && t > 0 && tid < 2)
                __hip_atomic_fetch_add(&cons[tid ? f1ix : f0ix], 1,
                                       __ATOMIC_RELAXED, __HIP_MEMORY_SCOPE_AGENT);

            // ---- L2: 256 -> 256, i=4 feat-tiles (64 feats/wave), row-half split ----
            {
                floatx4 a2[4][2];
                #pragma unroll
                for (int i = 0; i < 4; i++) {
                    int fb = (mtg*4 + i)*16 + quad*4;
                    floatx4 bv = *(const floatx4*)&cns[256 + fb];
                    #pragma unroll
                    for (int jj = 0; jj < 2; jj++) a2[i][jj] = bv;
                }
                #pragma unroll
                for (int kk = 0; kk < 8; kk++)
                    #pragma unroll
                    for (int jj = 0; jj < 2; jj++) {
                        int j = rh*2 + jj;
                        if (j < cnt) {
                            half8 bf = *(const half8*)&H1[(j*16 + cl)*256 + ((kk*32 + quad*8) ^ SW(cl))];
                            #pragma unroll
                            for (int i = 0; i < 4; i++)
                                a2[i][jj] = __builtin_amdgcn_mfma_f32_16x16x32_f16(w2f[i][kk], bf, a2[i][jj], 0,0,0);
                        }
                    }
                #pragma unroll
                for (int i = 0; i < 4; i++) {
                    int fb = (mtg*4 + i)*16 + quad*4;
                    #pragma unroll
                    for (int jj = 0; jj < 2; jj++) {
                        int j = rh*2 + jj;
                        if (j < cnt) {
                            int rl = j*16 + cl;
                            half4v pk;
                            #pragma unroll
                            for (int r = 0; r < 4; r++)
                                pk[r] = (_Float16)fmaxf(a2[i][jj][r], 0.f);
                            *(half4v*)&H2[rl*256 + (fb ^ SW(cl))] = pk;
                        }
                    }
                }
            }
            __syncthreads();   // L2 done

            // ---- L3: 256 -> 64, tanh, state -> global (w3 frags from LDS) ----
            {
                int f3 = mt3*16 + quad*4;
                floatx4 bv = *(const floatx4*)&cns[512 + f3];
                floatx4 a3[2];
                #pragma unroll
                for (int jj = 0; jj < 2; jj++) a3[jj] = bv;
                #pragma unroll
                for (int kk = 0; kk < 8; kk++) {
                    half8 wk = *(const half8*)&w3l[(mt3*8 + kk)*512 + lane*8];
                    #pragma unroll
                    for (int jj = 0; jj < 2; jj++) {
                        int j = half*2 + jj;
                        if (j < cnt) {
                            half8 bf = *(const half8*)&H2[(j*16 + cl)*256 + ((kk*32 + quad*8) ^ SW(cl))];
                            a3[jj] = __builtin_amdgcn_mfma_f32_16x16x32_f16(wk, bf, a3[jj], 0,0,0);
                        }
                    }
                }
                #pragma unroll
                for (int jj = 0; jj < 2; jj++) {
                    int j = half*2 + jj;
                    if (j < cnt) {
                        int grow = r0 + base16 + j*16 + cl;
                        union { _Float16 hh[4]; u64 q; } pk;
                        #pragma unroll
                        for (int r = 0; r < 4; r++) pk.hh[r] = (_Float16)fast_tanh(a3[jj][r]);
                        AGENT_ST((u64*)(Sg + ((size_t)(((t&1)*5 + n)*8192 + grow))*64 + f3), pk.q);
                    }
                }
            }
            // no barrier: next chunk's L1 writes H1 (disjoint from H2 readers)
        }

        // ---- publish: barrier drains vmcnt(0) for all waves, then flag ----
        __syncthreads();
        if (tid == 0)
            AGENT_ST(&flags[myix], t+1);
    }
}

__global__ __launch_bounds__(512, 2) void scan_kernel(
    const float* __restrict__ x, const float* __restrict__ W1,
    const float* __restrict__ b1, const float* __restrict__ b2, const float* __restrict__ b3,
    const _Float16* __restrict__ w1p, const _Float16* __restrict__ w2p,
    const _Float16* __restrict__ w3p,
    _Float16* __restrict__ Sg, int* flags, int* cons)
{
    extern __shared__ char smem[];
    int b = blockIdx.x;
    int n = b / NB, idx = b % NB;
    int r0 = idx < 2 ? idx*176 : 352 + (idx-2)*160;
    if (idx < 2)
        scan_impl<11>(x, W1, b1, b2, b3, w1p, w2p, w3p, Sg, flags, cons, smem, n, idx, r0);
    else
        scan_impl<10>(x, W1, b1, b2, b3, w1p, w2p, w3p, Sg, flags, cons, smem, n, idx, r0);
}

// ---------------- hpre: relu([x_127, states] @ Wo1 + bo1) ----------------
__global__ __launch_bounds__(512) void hpre_kernel(
    const float* __restrict__ x, const float* __restrict__ Wo1, const float* __restrict__ bo1,
    const _Float16* __restrict__ wo1p, const _Float16* __restrict__ Sg,
    float* __restrict__ hpre)
{
    __shared__ float x5[640];     // [5][128]
    __shared__ float wxo[1280];   // Wo1 rows 0..4
    __shared__ float bo1c[256];
    int tid = threadIdx.x, w = tid >> 6, lane = tid & 63;
    int quad = lane >> 4, cl = lane & 15;
    int r0h = blockIdx.x * 128;

    for (int i = tid; i < 640; i += 512)
        x5[i] = x[(size_t)(r0h + (i & 127))*640 + (i >> 7)*128 + 127];
    for (int i = tid; i < 1280; i += 512) wxo[i] = Wo1[i];
    if (tid < 256) bo1c[tid] = bo1[tid];

    half8 of[2][10];
    #pragma unroll
    for (int i = 0; i < 2; i++) {
        int mt = 2*w + i;
        #pragma unroll
        for (int kk = 0; kk < 10; kk++)
            of[i][kk] = *(const half8*)(wo1p + (size_t)(mt*10 + kk)*512 + lane*8);
    }
    __syncthreads();

    floatx4 acc[2][8];
    #pragma unroll
    for (int i = 0; i < 2; i++) {
        int fb = (2*w + i)*16 + quad*4;
        floatx4 bv = *(const floatx4*)&bo1c[fb];
        #pragma unroll
        for (int nt = 0; nt < 8; nt++) {
            floatx4 a = bv;
            #pragma unroll
            for (int p = 0; p < 5; p++) {
                floatx4 wv = *(const floatx4*)&wxo[p*256 + fb];
                float xv = x5[p*128 + nt*16 + cl];
                a += wv * xv;
            }
            acc[i][nt] = a;
        }
    }
    #pragma unroll
    for (int kk = 0; kk < 10; kk++) {
        int nd = kk >> 1;
        #pragma unroll
        for (int nt = 0; nt < 8; nt++) {
            const _Float16* sp = Sg + ((size_t)((5 + nd)*8192 + r0h + nt*16 + cl))*64
                                    + (kk & 1)*32 + quad*8;   // buf 1 = state(127)
            half8 bf = *(const half8*)sp;
            acc[0][nt] = __builtin_amdgcn_mfma_f32_16x16x32_f16(of[0][kk], bf, acc[0][nt], 0,0,0);
            acc[1][nt] = __builtin_amdgcn_mfma_f32_16x16x32_f16(of[1][kk], bf, acc[1][nt], 0,0,0);
        }
    }
    #pragma unroll
    for (int i = 0; i < 2; i++) {
        int fb = (2*w + i)*16 + quad*4;
        #pragma unroll
        for (int nt = 0; nt < 8; nt++) {
            floatx4 v = acc[i][nt];
            #pragma unroll
            for (int r = 0; r < 4; r++) v[r] = fmaxf(v[r], 0.f);
            *(floatx4*)&hpre[(size_t)(r0h + nt*16 + cl)*256 + fb] = v;
        }
    }
}

// ---------------- BN stats ----------------
__global__ __launch_bounds__(256) void bnstats_kernel(const float* __restrict__ hpre,
                                                      float* __restrict__ sums)
{
    int col = threadIdx.x;
    int r0 = blockIdx.x * 128;
    float s = 0.f, s2 = 0.f;
    for (int r = 0; r < 128; r++) {
        float v = hpre[(size_t)(r0 + r)*256 + col];
        s += v; s2 += v*v;
    }
    atomicAdd(&sums[col], s);
    atomicAdd(&sums[256 + col], s2);
}

// ---------------- normalize + Wo2 + softmax ----------------
__global__ __launch_bounds__(256) void head_kernel(
    const float* __restrict__ hpre, const float* __restrict__ sums,
    const float* __restrict__ gamma, const float* __restrict__ beta,
    const float* __restrict__ Wo2, const float* __restrict__ bo2,
    float* __restrict__ out)
{
    int row  = blockIdx.x * 4 + (threadIdx.x >> 6);
    int lane = threadIdx.x & 63;
    floatx4 h  = *(const floatx4*)&hpre[(size_t)row*256 + lane*4];
    floatx4 sm = *(const floatx4*)&sums[lane*4];
    floatx4 sq = *(const floatx4*)&sums[256 + lane*4];
    floatx4 g  = *(const floatx4*)&gamma[lane*4];
    floatx4 bb = *(const floatx4*)&beta[lane*4];
    float acc[7] = {0.f,0.f,0.f,0.f,0.f,0.f,0.f};
    #pragma unroll
    for (int e = 0; e < 4; e++) {
        float mu  = sm[e] * (1.f/8192.f);
        float var = sq[e] * (1.f/8192.f) - mu*mu;
        float hn  = (h[e] - mu) * rsqrtf(var + 1e-5f) * g[e] + bb[e];
        int colg = lane*4 + e;
        #pragma unroll
        for (int j = 0; j < 7; j++) acc[j] += hn * Wo2[colg*7 + j];
    }
    #pragma unroll
    for (int off = 1; off < 64; off <<= 1) {
        #pragma unroll
        for (int j = 0; j < 7; j++) acc[j] += __shfl_xor(acc[j], off, 64);
    }
    float z[7], m = -1e30f;
    #pragma unroll
    for (int j = 0; j < 7; j++) { z[j] = acc[j] + bo2[j]; m = fmaxf(m, z[j]); }
    float se = 0.f;
    #pragma unroll
    for (int j = 0; j < 7; j++) { z[j] = expf(z[j] - m); se += z[j]; }
    if (lane < 7) out[(size_t)row*7 + lane] = z[lane] / se;
}

extern "C" void kernel_launch(void* const* d_in, const int* in_sizes, int n_in,
                              void* d_out, int out_size, void* d_ws, size_t ws_size,
                              hipStream_t stream)
{
    const float* x    = (const float*)d_in[0];
    const float* W1   = (const float*)d_in[1];
    const float* b1   = (const float*)d_in[2];
    const float* W2   = (const float*)d_in[3];
    const float* b2   = (const float*)d_in[4];
    const float* W3   = (const float*)d_in[5];
    const float* b3   = (const float*)d_in[6];
    const float* Wo1  = (const float*)d_in[7];
    const float* bo1  = (const float*)d_in[8];
    const float* gamma= (const float*)d_in[9];
    const float* beta = (const float*)d_in[10];
    const float* Wo2  = (const float*)d_in[11];
    const float* bo2  = (const float*)d_in[12];
    float* out = (float*)d_out;

    if (ws_size < WS_NEEDED) return;
    char* ws = (char*)d_ws;
    float*     hpre  = (float*)(ws + HPRE_OFF);
    float*     sums  = (float*)(ws + SUM_OFF);
    int*       flags = (int*)(ws + FLAG_OFF);
    int*       cons  = (int*)(ws + CONS_OFF);
    _Float16*  Sg    = (_Float16*)(ws + SG_OFF);
    _Float16*  w1p   = (_Float16*)(ws + PACK_OFF);
    _Float16*  w2p   = w1p + W1P_HALFS;
    _Float16*  w3p   = w2p + W2P_HALFS;
    _Float16*  wo1p  = w3p + W3P_HALFS;

    hipFuncSetAttribute((const void*)scan_kernel,
                        hipFuncAttributeMaxDynamicSharedMemorySize, SMEM_BYTES);

    pack_kernel<<<320, 256, 0, stream>>>(W1, W2, W3, Wo1, w1p, w2p, w3p, wo1p,
                                         sums, flags, cons);
    scan_kernel<<<5*NB, 512, SMEM_BYTES, stream>>>(x, W1, b1, b2, b3,
                                                   w1p, w2p, w3p, Sg, flags, cons);
    hpre_kernel<<<64, 512, 0, stream>>>(x, Wo1, bo1, wo1p, Sg, hpre);
    bnstats_kernel<<<64, 256, 0, stream>>>(hpre, sums);
    head_kernel<<<2048, 256, 0, stream>>>(hpre, sums, gamma, beta, Wo2, bo2, out);
}

// Round 7
// 2418.938 us; speedup vs baseline: 1.2813x; 1.0322x over previous
//
#include <hip/hip_runtime.h>
#include <cstddef>
#include <cstdint>

typedef _Float16 half8  __attribute__((ext_vector_type(8)));
typedef _Float16 half4v __attribute__((ext_vector_type(4)));
typedef float    floatx4 __attribute__((ext_vector_type(4)));
typedef unsigned long long u64;

#define NB 51                       // blocks per node, grid = 5*NB = 255
#define SW(row) (((row)&7)*8)       // LDS xor-swizzle (8-half granules)

#define AGENT_LD(p)    __hip_atomic_load((p), __ATOMIC_RELAXED, __HIP_MEMORY_SCOPE_AGENT)
#define AGENT_ST(p,v)  __hip_atomic_store((p), (v), __ATOMIC_RELAXED, __HIP_MEMORY_SCOPE_AGENT)

// ---- ws layout (bytes) ----
#define HPRE_OFF 0u                 // 8192*256 f32
#define SUM_OFF  8388608u           // 512 f32
#define FLAG_OFF 8390656u           // 256 int
#define CONS_OFF 8391680u           // 256 int
#define SG_OFF   8392704u           // 2*5*8192*64 f16 = 10485760
#define PACK_OFF 18878464u
#define W1P_HALFS 163840
#define W2P_HALFS 327680
#define W3P_HALFS 81920
#define WS_NEEDED 20189184u

// ---- dynamic smem layout for scan (bytes) ----
// Sp  [2][176][64] f16 = 45056
// H1  [64][256] f16    = 32768
// H2  [64][256] f16    = 32768
// xls [2][176] f32     = 1408
// cns [1088] f32       = 4352
// w3l 32 frags f16     = 32768
#define SMEM_BYTES 149120

__device__ __forceinline__ float fast_tanh(float v) {
    v = fminf(fmaxf(v, -15.f), 15.f);
    float a = exp2f(v * 2.88539008177793f);   // e^{2v}
    return (a - 1.f) / (a + 1.f);
}

// ---------------- pack: f32 weights -> f16 MFMA A-fragment order ----------------
__global__ __launch_bounds__(256) void pack_kernel(
    const float* __restrict__ W1, const float* __restrict__ W2,
    const float* __restrict__ W3, const float* __restrict__ Wo1,
    _Float16* __restrict__ w1p, _Float16* __restrict__ w2p,
    _Float16* __restrict__ w3p, _Float16* __restrict__ wo1p,
    float* __restrict__ sums, int* __restrict__ flags, int* __restrict__ cons)
{
    int id = blockIdx.x * 256 + threadIdx.x;
    if (id < 512) sums[id] = 0.f;
    if (id < 256) { flags[id] = 0; cons[id] = 0; }
    int f = id >> 6;
    int lane = id & 63;
    int q = lane >> 4, cl = lane & 15;
    if (f < 320) {                           // W1 state rows
        int kk = f & 3, mt = (f >> 2) & 15, n = f >> 6;
        #pragma unroll
        for (int j = 0; j < 8; j++)
            w1p[(size_t)f*512 + lane*8 + j] =
                (_Float16)W1[(size_t)(n*130 + 2 + kk*32 + q*8 + j)*256 + mt*16 + cl];
    } else if (f < 960) {                    // W2
        int g = f - 320;
        int kk = g & 7, mt = (g >> 3) & 15, n = g >> 7;
        #pragma unroll
        for (int j = 0; j < 8; j++)
            w2p[(size_t)g*512 + lane*8 + j] =
                (_Float16)W2[(size_t)(n*256 + kk*32 + q*8 + j)*256 + mt*16 + cl];
    } else if (f < 1120) {                   // W3
        int g = f - 960;
        int kk = g & 7, mt = (g >> 3) & 3, n = g >> 5;
        #pragma unroll
        for (int j = 0; j < 8; j++)
            w3p[(size_t)g*512 + lane*8 + j] =
                (_Float16)W3[(size_t)(n*256 + kk*32 + q*8 + j)*64 + mt*16 + cl];
    } else if (f < 1280) {                   // Wo1 state rows
        int g = f - 1120;
        int kk = g % 10, mt = g / 10;
        #pragma unroll
        for (int j = 0; j < 8; j++)
            wo1p[(size_t)g*512 + lane*8 + j] =
                (_Float16)Wo1[(size_t)(5 + kk*32 + q*8 + j)*256 + mt*16 + cl];
    }
}

// ---------------- scan: node-specialized persistent blocks ----------------
// Chunk-granular flag protocol: flags[b] = 3t+c+1 after block b's step-t
// chunk-c state stores are drained (posted at the first barrier after the
// stores).  Consumer stages parent chunk c of step t-1 once flag >= 3(t-1)+c+1,
// staged inside the L2 window (drained at L2-end barrier, read at next L1).
// Every dependency edge has >= ~0.45 step of slack -> jitter absorbed.
template<int NT>
__device__ __attribute__((always_inline)) void scan_impl(
    const float* __restrict__ x, const float* __restrict__ W1,
    const float* __restrict__ b1, const float* __restrict__ b2, const float* __restrict__ b3,
    const _Float16* __restrict__ w1p, const _Float16* __restrict__ w2p,
    const _Float16* __restrict__ w3p,
    _Float16* __restrict__ Sg, int* flags, int* cons,
    char* smem, int n, int idx, int r0)
{
    constexpr int BB  = NT * 16;
    constexpr int NCH = 3;
    _Float16* Sp  = (_Float16*)smem;                 // [2][176][64] swizzled
    _Float16* H1  = (_Float16*)(smem + 45056);
    _Float16* H2  = (_Float16*)(smem + 77824);
    float*    xls = (float*)(smem + 110592);         // [2][176]
    float*    cns = (float*)(smem + 112000);         // 1088 floats
    _Float16* w3l = (_Float16*)(smem + 116352);      // 32 w3 A-frags

    const int tid = threadIdx.x, w = tid >> 6, lane = tid & 63;
    const int quad = lane >> 4, cl = lane & 15;
    const int P0t[5] = {3,0,0,1,2}, P1t[5] = {4,4,1,2,3};
    const int p0 = P0t[n], p1 = P1t[n];
    const int myix = n*NB + idx, f0ix = p0*NB + idx, f1ix = p1*NB + idx;
    const int mt3 = w & 3, half = w >> 2;
    const int mtg = w & 3, rh = w >> 2;      // L2 roles: feat-group, row-half

    // ---- resident weight fragments (loaded once) ----
    half8 w1f[2][4], w2f[4][8];
    #pragma unroll
    for (int i = 0; i < 2; i++) {
        int mt = 2*w + i;
        #pragma unroll
        for (int kk = 0; kk < 4; kk++)
            w1f[i][kk] = *(const half8*)(w1p + (size_t)((n*16 + mt)*4 + kk)*512 + lane*8);
    }
    #pragma unroll
    for (int i = 0; i < 4; i++) {
        int mt = mtg*4 + i;
        #pragma unroll
        for (int kk = 0; kk < 8; kk++)
            w2f[i][kk] = *(const half8*)(w2p + (size_t)((n*16 + mt)*8 + kk)*512 + lane*8);
    }

    // ---- stage w3 frags into LDS ----
    for (int i = tid; i < 16384; i += 512) w3l[i] = w3p[(size_t)n*16384 + i];

    // ---- stage per-node constants ----
    for (int i = tid; i < 1088; i += 512) {
        float v;
        if      (i < 256) v = b1[n*256 + i];
        else if (i < 512) v = b2[n*256 + i - 256];
        else if (i < 576) v = b3[n*64  + i - 512];
        else { int j = i - 576; v = W1[(size_t)(n*130 + (j>>8))*256 + (j & 255)]; }
        cns[i] = v;
    }

    auto stage_rows = [&](int first_row, int R, int buf) {
        int tot = 2*R*8;
        for (int i = tid; i < tot; i += 512) {
            int pp = i >= R*8;
            int rem = i - pp*R*8;
            int rl = rem >> 3, g8 = rem & 7;
            int grow = first_row + rl;
            u64* src = (u64*)(Sg + ((size_t)((buf*5 + (pp ? p1 : p0))*8192 + r0 + grow))*64 + g8*8);
            u64 lo = AGENT_LD(src);
            u64 hi = AGENT_LD(src + 1);
            union { u64 q[2]; half8 h; } u; u.q[0] = lo; u.q[1] = hi;
            *(half8*)&Sp[pp*11264 + grow*64 + ((g8*8) ^ SW(grow))] = u.h;
        }
    };

    for (int t = 0; t < 128; t++) {
        // ---- phase 0: wait for parents' chunk-0 of step t-1, and cons guard ----
        if (t > 0 && tid < 2) {
            int* fp = &flags[tid ? f1ix : f0ix];
            int need = 3*t - 2;              // = 3(t-1)+1
            while (AGENT_LD(fp) < need) __builtin_amdgcn_s_sleep(2);
        }
        if (t >= 2 && tid == 2) {
            int need = 2*(t-1);
            while (AGENT_LD(&cons[myix]) < need) __builtin_amdgcn_s_sleep(2);
        }
        __syncthreads();

        // ---- phase 1: stage chunk-0 parent rows + x_t ----
        if (t > 0) stage_rows(0, 64, (t-1) & 1);
        for (int i = tid; i < 2*BB; i += 512) {
            int pp = i >= BB; int rl = i - pp*BB;
            xls[pp*176 + rl] = x[(size_t)(r0 + rl)*640 + (pp ? p1 : p0)*128 + t];
        }
        __syncthreads();

        // ---- phase 2: chunks of 4 row-tiles: L1 -> (stage next + L2) -> L3 ----
        #pragma unroll
        for (int c = 0; c < NCH; c++) {
            const int rem_nt = NT - c*4;
            const int cnt = rem_nt < 4 ? rem_nt : 4;
            const int base16 = c*64;

            // dedicated lanes (waves 1,2) pre-check next chunk's parent flag
            if (t > 0 && c + 1 < NCH) {
                int sw0 = (c+1)*64;
                if (tid == sw0 || tid == sw0+1) {
                    int* fp = &flags[(tid == sw0) ? f0ix : f1ix];
                    int need = 3*t + c - 1;  // = 3(t-1)+(c+1)+1 - 3 .. i.e. 3(t-1)+c+2
                    while (AGENT_LD(fp) < need) __builtin_amdgcn_s_sleep(2);
                }
            }

            // ---- L1: i=2 feat-tiles (32 feats/wave), all row-tiles ----
            {
                floatx4 a1[2][4];
                #pragma unroll
                for (int i = 0; i < 2; i++) {
                    int fb = (2*w + i)*16 + quad*4;
                    floatx4 bv = *(const floatx4*)&cns[fb];
                    floatx4 u0 = *(const floatx4*)&cns[576 + fb];
                    floatx4 u1 = *(const floatx4*)&cns[832 + fb];
                    #pragma unroll
                    for (int j = 0; j < 4; j++) if (j < cnt) {
                        int rb = base16 + j*16 + cl;
                        float xa = xls[rb], xc = xls[176 + rb];
                        a1[i][j] = bv + u0*xa + u1*xc;
                    }
                }
                if (t > 0) {
                    #pragma unroll
                    for (int kk = 0; kk < 4; kk++)
                        #pragma unroll
                        for (int j = 0; j < 4; j++) if (j < cnt) {
                            half8 bf = *(const half8*)&Sp[(kk>>1)*11264 + (base16 + j*16 + cl)*64
                                                          + (((kk&1)*32 + quad*8) ^ SW(cl))];
                            a1[0][j] = __builtin_amdgcn_mfma_f32_16x16x32_f16(w1f[0][kk], bf, a1[0][j], 0,0,0);
                            a1[1][j] = __builtin_amdgcn_mfma_f32_16x16x32_f16(w1f[1][kk], bf, a1[1][j], 0,0,0);
                        }
                }
                #pragma unroll
                for (int i = 0; i < 2; i++) {
                    int fb = (2*w + i)*16 + quad*4;
                    #pragma unroll
                    for (int j = 0; j < 4; j++) if (j < cnt) {
                        int rl = j*16 + cl;
                        half4v pk;
                        #pragma unroll
                        for (int r = 0; r < 4; r++)
                            pk[r] = (_Float16)fmaxf(a1[i][j][r], 0.f);
                        *(half4v*)&H1[rl*256 + (fb ^ SW(cl))] = pk;
                    }
                }
            }
            __syncthreads();   // L1 done; chunk c-1 L3 stores drained here

            // publish chunk c-1 (stores drained at the barrier above)
            if (c >= 1 && tid == 0)
                AGENT_ST(&flags[myix], 3*t + c);

            // stage next chunk's parent rows (overlaps L2 compute)
            if (t > 0 && c + 1 < NCH) {
                int fr = (c+1)*64;
                int R = BB - fr; if (R > 64) R = 64;
                stage_rows(fr, R, (t-1) & 1);
            }

            // ---- L2: 256 -> 256, i=4 feat-tiles (64 feats/wave), row-half split ----
            {
                floatx4 a2[4][2];
                #pragma unroll
                for (int i = 0; i < 4; i++) {
                    int fb = (mtg*4 + i)*16 + quad*4;
                    floatx4 bv = *(const floatx4*)&cns[256 + fb];
                    #pragma unroll
                    for (int jj = 0; jj < 2; jj++) a2[i][jj] = bv;
                }
                #pragma unroll
                for (int kk = 0; kk < 8; kk++)
                    #pragma unroll
                    for (int jj = 0; jj < 2; jj++) {
                        int j = rh*2 + jj;
                        if (j < cnt) {
                            half8 bf = *(const half8*)&H1[(j*16 + cl)*256 + ((kk*32 + quad*8) ^ SW(cl))];
                            #pragma unroll
                            for (int i = 0; i < 4; i++)
                                a2[i][jj] = __builtin_amdgcn_mfma_f32_16x16x32_f16(w2f[i][kk], bf, a2[i][jj], 0,0,0);
                        }
                    }
                #pragma unroll
                for (int i = 0; i < 4; i++) {
                    int fb = (mtg*4 + i)*16 + quad*4;
                    #pragma unroll
                    for (int jj = 0; jj < 2; jj++) {
                        int j = rh*2 + jj;
                        if (j < cnt) {
                            int rl = j*16 + cl;
                            half4v pk;
                            #pragma unroll
                            for (int r = 0; r < 4; r++)
                                pk[r] = (_Float16)fmaxf(a2[i][jj][r], 0.f);
                            *(half4v*)&H2[rl*256 + (fb ^ SW(cl))] = pk;
                        }
                    }
                }
            }
            __syncthreads();   // L2 done; staging of chunk c+1 drained here

            // all staging for this step drained -> release producers
            if (c == 1 && t > 0 && tid < 2)
                __hip_atomic_fetch_add(&cons[tid ? f1ix : f0ix], 1,
                                       __ATOMIC_RELAXED, __HIP_MEMORY_SCOPE_AGENT);

            // ---- L3: 256 -> 64, tanh, state -> global (w3 frags from LDS) ----
            {
                int f3 = mt3*16 + quad*4;
                floatx4 bv = *(const floatx4*)&cns[512 + f3];
                floatx4 a3[2];
                #pragma unroll
                for (int jj = 0; jj < 2; jj++) a3[jj] = bv;
                #pragma unroll
                for (int kk = 0; kk < 8; kk++) {
                    half8 wk = *(const half8*)&w3l[(mt3*8 + kk)*512 + lane*8];
                    #pragma unroll
                    for (int jj = 0; jj < 2; jj++) {
                        int j = half*2 + jj;
                        if (j < cnt) {
                            half8 bf = *(const half8*)&H2[(j*16 + cl)*256 + ((kk*32 + quad*8) ^ SW(cl))];
                            a3[jj] = __builtin_amdgcn_mfma_f32_16x16x32_f16(wk, bf, a3[jj], 0,0,0);
                        }
                    }
                }
                #pragma unroll
                for (int jj = 0; jj < 2; jj++) {
                    int j = half*2 + jj;
                    if (j < cnt) {
                        int grow = r0 + base16 + j*16 + cl;
                        union { _Float16 hh[4]; u64 q; } pk;
                        #pragma unroll
                        for (int r = 0; r < 4; r++) pk.hh[r] = (_Float16)fast_tanh(a3[jj][r]);
                        AGENT_ST((u64*)(Sg + ((size_t)(((t&1)*5 + n)*8192 + grow))*64 + f3), pk.q);
                    }
                }
            }
        }

        // ---- end of step: drain last chunk's stores, publish final chunk ----
        __syncthreads();
        if (tid == 0)
            AGENT_ST(&flags[myix], 3*t + 3);
    }
}

__global__ __launch_bounds__(512)
__attribute__((amdgpu_waves_per_eu(2, 2)))
void scan_kernel(
    const float* __restrict__ x, const float* __restrict__ W1,
    const float* __restrict__ b1, const float* __restrict__ b2, const float* __restrict__ b3,
    const _Float16* __restrict__ w1p, const _Float16* __restrict__ w2p,
    const _Float16* __restrict__ w3p,
    _Float16* __restrict__ Sg, int* flags, int* cons)
{
    extern __shared__ char smem[];
    int b = blockIdx.x;
    int n = b / NB, idx = b % NB;
    int r0 = idx < 2 ? idx*176 : 352 + (idx-2)*160;
    if (idx < 2)
        scan_impl<11>(x, W1, b1, b2, b3, w1p, w2p, w3p, Sg, flags, cons, smem, n, idx, r0);
    else
        scan_impl<10>(x, W1, b1, b2, b3, w1p, w2p, w3p, Sg, flags, cons, smem, n, idx, r0);
}

// ---------------- hpre: relu([x_127, states] @ Wo1 + bo1) ----------------
__global__ __launch_bounds__(512) void hpre_kernel(
    const float* __restrict__ x, const float* __restrict__ Wo1, const float* __restrict__ bo1,
    const _Float16* __restrict__ wo1p, const _Float16* __restrict__ Sg,
    float* __restrict__ hpre)
{
    __shared__ float x5[640];     // [5][128]
    __shared__ float wxo[1280];   // Wo1 rows 0..4
    __shared__ float bo1c[256];
    int tid = threadIdx.x, w = tid >> 6, lane = tid & 63;
    int quad = lane >> 4, cl = lane & 15;
    int r0h = blockIdx.x * 128;

    for (int i = tid; i < 640; i += 512)
        x5[i] = x[(size_t)(r0h + (i & 127))*640 + (i >> 7)*128 + 127];
    for (int i = tid; i < 1280; i += 512) wxo[i] = Wo1[i];
    if (tid < 256) bo1c[tid] = bo1[tid];

    half8 of[2][10];
    #pragma unroll
    for (int i = 0; i < 2; i++) {
        int mt = 2*w + i;
        #pragma unroll
        for (int kk = 0; kk < 10; kk++)
            of[i][kk] = *(const half8*)(wo1p + (size_t)(mt*10 + kk)*512 + lane*8);
    }
    __syncthreads();

    floatx4 acc[2][8];
    #pragma unroll
    for (int i = 0; i < 2; i++) {
        int fb = (2*w + i)*16 + quad*4;
        floatx4 bv = *(const floatx4*)&bo1c[fb];
        #pragma unroll
        for (int nt = 0; nt < 8; nt++) {
            floatx4 a = bv;
            #pragma unroll
            for (int p = 0; p < 5; p++) {
                floatx4 wv = *(const floatx4*)&wxo[p*256 + fb];
                float xv = x5[p*128 + nt*16 + cl];
                a += wv * xv;
            }
            acc[i][nt] = a;
        }
    }
    #pragma unroll
    for (int kk = 0; kk < 10; kk++) {
        int nd = kk >> 1;
        #pragma unroll
        for (int nt = 0; nt < 8; nt++) {
            const _Float16* sp = Sg + ((size_t)((5 + nd)*8192 + r0h + nt*16 + cl))*64
                                    + (kk & 1)*32 + quad*8;   // buf 1 = state(127)
            half8 bf = *(const half8*)sp;
            acc[0][nt] = __builtin_amdgcn_mfma_f32_16x16x32_f16(of[0][kk], bf, acc[0][nt], 0,0,0);
            acc[1][nt] = __builtin_amdgcn_mfma_f32_16x16x32_f16(of[1][kk], bf, acc[1][nt], 0,0,0);
        }
    }
    #pragma unroll
    for (int i = 0; i < 2; i++) {
        int fb = (2*w + i)*16 + quad*4;
        #pragma unroll
        for (int nt = 0; nt < 8; nt++) {
            floatx4 v = acc[i][nt];
            #pragma unroll
            for (int r = 0; r < 4; r++) v[r] = fmaxf(v[r], 0.f);
            *(floatx4*)&hpre[(size_t)(r0h + nt*16 + cl)*256 + fb] = v;
        }
    }
}

// ---------------- BN stats ----------------
__global__ __launch_bounds__(256) void bnstats_kernel(const float* __restrict__ hpre,
                                                      float* __restrict__ sums)
{
    int col = threadIdx.x;
    int r0 = blockIdx.x * 128;
    float s = 0.f, s2 = 0.f;
    for (int r = 0; r < 128; r++) {
        float v = hpre[(size_t)(r0 + r)*256 + col];
        s += v; s2 += v*v;
    }
    atomicAdd(&sums[col], s);
    atomicAdd(&sums[256 + col], s2);
}

// ---------------- normalize + Wo2 + softmax ----------------
__global__ __launch_bounds__(256) void head_kernel(
    const float* __restrict__ hpre, const float* __restrict__ sums,
    const float* __restrict__ gamma, const float* __restrict__ beta,
    const float* __restrict__ Wo2, const float* __restrict__ bo2,
    float* __restrict__ out)
{
    int row  = blockIdx.x * 4 + (threadIdx.x >> 6);
    int lane = threadIdx.x & 63;
    floatx4 h  = *(const floatx4*)&hpre[(size_t)row*256 + lane*4];
    floatx4 sm = *(const floatx4*)&sums[lane*4];
    floatx4 sq = *(const floatx4*)&sums[256 + lane*4];
    floatx4 g  = *(const floatx4*)&gamma[lane*4];
    floatx4 bb = *(const floatx4*)&beta[lane*4];
    float acc[7] = {0.f,0.f,0.f,0.f,0.f,0.f,0.f};
    #pragma unroll
    for (int e = 0; e < 4; e++) {
        float mu  = sm[e] * (1.f/8192.f);
        float var = sq[e] * (1.f/8192.f) - mu*mu;
        float hn  = (h[e] - mu) * rsqrtf(var + 1e-5f) * g[e] + bb[e];
        int colg = lane*4 + e;
        #pragma unroll
        for (int j = 0; j < 7; j++) acc[j] += hn * Wo2[colg*7 + j];
    }
    #pragma unroll
    for (int off = 1; off < 64; off <<= 1) {
        #pragma unroll
        for (int j = 0; j < 7; j++) acc[j] += __shfl_xor(acc[j], off, 64);
    }
    float z[7], m = -1e30f;
    #pragma unroll
    for (int j = 0; j < 7; j++) { z[j] = acc[j] + bo2[j]; m = fmaxf(m, z[j]); }
    float se = 0.f;
    #pragma unroll
    for (int j = 0; j < 7; j++) { z[j] = expf(z[j] - m); se += z[j]; }
    if (lane < 7) out[(size_t)row*7 + lane] = z[lane] / se;
}

extern "C" void kernel_launch(void* const* d_in, const int* in_sizes, int n_in,
                              void* d_out, int out_size, void* d_ws, size_t ws_size,
                              hipStream_t stream)
{
    const float* x    = (const float*)d_in[0];
    const float* W1   = (const float*)d_in[1];
    const float* b1   = (const float*)d_in[2];
    const float* W2   = (const float*)d_in[3];
    const float* b2   = (const float*)d_in[4];
    const float* W3   = (const float*)d_in[5];
    const float* b3   = (const float*)d_in[6];
    const float* Wo1  = (const float*)d_in[7];
    const float* bo1  = (const float*)d_in[8];
    const float* gamma= (const float*)d_in[9];
    const float* beta = (const float*)d_in[10];
    const float* Wo2  = (const float*)d_in[11];
    const float* bo2  = (const float*)d_in[12];
    float* out = (float*)d_out;

    if (ws_size < WS_NEEDED) return;
    char* ws = (char*)d_ws;
    float*     hpre  = (float*)(ws + HPRE_OFF);
    float*     sums  = (float*)(ws + SUM_OFF);
    int*       flags = (int*)(ws + FLAG_OFF);
    int*       cons  = (int*)(ws + CONS_OFF);
    _Float16*  Sg    = (_Float16*)(ws + SG_OFF);
    _Float16*  w1p   = (_Float16*)(ws + PACK_OFF);
    _Float16*  w2p   = w1p + W1P_HALFS;
    _Float16*  w3p   = w2p + W2P_HALFS;
    _Float16*  wo1p  = w3p + W3P_HALFS;

    hipFuncSetAttribute((const void*)scan_kernel,
                        hipFuncAttributeMaxDynamicSharedMemorySize, SMEM_BYTES);

    pack_kernel<<<320, 256, 0, stream>>>(W1, W2, W3, Wo1, w1p, w2p, w3p, wo1p,
                                         sums, flags, cons);
    scan_kernel<<<5*NB, 512, SMEM_BYTES, stream>>>(x, W1, b1, b2, b3,
                                                   w1p, w2p, w3p, Sg, flags, cons);
    hpre_kernel<<<64, 512, 0, stream>>>(x, Wo1, bo1, wo1p, Sg, hpre);
    bnstats_kernel<<<64, 256, 0, stream>>>(hpre, sums);
    head_kernel<<<2048, 256, 0, stream>>>(hpre, sums, gamma, beta, Wo2, bo2, out);
}

// Round 8
// 1858.163 us; speedup vs baseline: 1.6680x; 1.3018x over previous
//
#include <hip/hip_runtime.h>
#include <cstddef>
#include <cstdint>

typedef _Float16 half8  __attribute__((ext_vector_type(8)));
typedef _Float16 half4v __attribute__((ext_vector_type(4)));
typedef float    floatx4 __attribute__((ext_vector_type(4)));
typedef unsigned long long u64;

#define NB 51                       // blocks per node, grid = 5*NB = 255
#define SW(row) (((row)&7)*8)       // LDS xor-swizzle (8-half granules)

#define AGENT_LD(p)    __hip_atomic_load((p), __ATOMIC_RELAXED, __HIP_MEMORY_SCOPE_AGENT)
#define AGENT_ST(p,v)  __hip_atomic_store((p), (v), __ATOMIC_RELAXED, __HIP_MEMORY_SCOPE_AGENT)

typedef __attribute__((address_space(3))) void lds_vt;
typedef const __attribute__((address_space(1))) void gbl_vt;
// aux=16 = SC1 bit (gfx940+ CPol: SC0=1, NT=2, SC1=16) -> agent-scope load,
// bypasses non-coherent L1/L2, served at LLC (same policy AGENT_LD lowers to).
#define DMA16_SC1(src, dst) \
    __builtin_amdgcn_global_load_lds((gbl_vt*)(src), (lds_vt*)(dst), 16, 0, 16)

// ---- ws layout (bytes) ----
#define HPRE_OFF 0u                 // 8192*256 f32
#define SUM_OFF  8388608u           // 512 f32
#define FLAG_OFF 8390656u           // 256 int
#define CONS_OFF 8391680u           // 256 int
#define SG_OFF   8392704u           // 2*5*8192*64 f16 = 10485760
#define PACK_OFF 18878464u
#define W1P_HALFS 163840
#define W2P_HALFS 327680
#define W3P_HALFS 81920
#define WS_NEEDED 20189184u

// ---- dynamic smem layout for scan (bytes) ----
// Sp  [2][176][64] f16 = 45056
// H1  [64][256] f16    = 32768
// H2  [64][256] f16    = 32768
// xls [2][2][176] f32  = 2816   (x_t double buffer)
// cns [1088] f32       = 4352
#define SMEM_BYTES 117760

__device__ __forceinline__ float fast_tanh(float v) {
    v = fminf(fmaxf(v, -15.f), 15.f);
    float a = exp2f(v * 2.88539008177793f);   // e^{2v}
    return (a - 1.f) / (a + 1.f);
}

// ---------------- pack: f32 weights -> f16 MFMA A-fragment order ----------------
// A-frag 16x16x32: lane holds A[m = mt*16 + (lane&15)][k = kk*32 + (lane>>4)*8 + j]
__global__ __launch_bounds__(256) void pack_kernel(
    const float* __restrict__ W1, const float* __restrict__ W2,
    const float* __restrict__ W3, const float* __restrict__ Wo1,
    _Float16* __restrict__ w1p, _Float16* __restrict__ w2p,
    _Float16* __restrict__ w3p, _Float16* __restrict__ wo1p,
    float* __restrict__ sums, int* __restrict__ flags, int* __restrict__ cons)
{
    int id = blockIdx.x * 256 + threadIdx.x;
    if (id < 512) sums[id] = 0.f;
    if (id < 256) { flags[id] = 0; cons[id] = 0; }
    int f = id >> 6;
    int lane = id & 63;
    int q = lane >> 4, cl = lane & 15;
    if (f < 320) {                           // W1 state rows
        int kk = f & 3, mt = (f >> 2) & 15, n = f >> 6;
        #pragma unroll
        for (int j = 0; j < 8; j++)
            w1p[(size_t)f*512 + lane*8 + j] =
                (_Float16)W1[(size_t)(n*130 + 2 + kk*32 + q*8 + j)*256 + mt*16 + cl];
    } else if (f < 960) {                    // W2
        int g = f - 320;
        int kk = g & 7, mt = (g >> 3) & 15, n = g >> 7;
        #pragma unroll
        for (int j = 0; j < 8; j++)
            w2p[(size_t)g*512 + lane*8 + j] =
                (_Float16)W2[(size_t)(n*256 + kk*32 + q*8 + j)*256 + mt*16 + cl];
    } else if (f < 1120) {                   // W3
        int g = f - 960;
        int kk = g & 7, mt = (g >> 3) & 3, n = g >> 5;
        #pragma unroll
        for (int j = 0; j < 8; j++)
            w3p[(size_t)g*512 + lane*8 + j] =
                (_Float16)W3[(size_t)(n*256 + kk*32 + q*8 + j)*64 + mt*16 + cl];
    } else if (f < 1280) {                   // Wo1 state rows
        int g = f - 1120;
        int kk = g % 10, mt = g / 10;
        #pragma unroll
        for (int j = 0; j < 8; j++)
            wo1p[(size_t)g*512 + lane*8 + j] =
                (_Float16)Wo1[(size_t)(5 + kk*32 + q*8 + j)*256 + mt*16 + cl];
    }
}

// ---------------- scan: node-specialized persistent blocks ----------------
// Round-4 protocol (proven best): one end-of-step flag, one cons back-edge.
// Staging now uses global_load_lds (SC1) issued by wave 0: no VGPR round-trip,
// swizzle realized by per-lane source-address permutation (lines stay coalesced),
// LDS write is lane-contiguous (conflict-free).  8 barriers/step.
template<int NT>
__device__ __attribute__((always_inline)) void scan_impl(
    const float* __restrict__ x, const float* __restrict__ W1,
    const float* __restrict__ b1, const float* __restrict__ b2, const float* __restrict__ b3,
    const _Float16* __restrict__ w1p, const _Float16* __restrict__ w2p,
    const _Float16* __restrict__ w3p,
    _Float16* __restrict__ Sg, int* flags, int* cons,
    char* smem, int n, int idx, int r0)
{
    constexpr int BB  = NT * 16;
    constexpr int NCH = 3;
    _Float16* Sp  = (_Float16*)smem;                 // [2][176][64] swizzled
    _Float16* H1  = (_Float16*)(smem + 45056);
    _Float16* H2  = (_Float16*)(smem + 77824);
    float*    xls = (float*)(smem + 110592);         // [2][2][176]
    float*    cns = (float*)(smem + 113408);         // 1088 floats

    const int tid = threadIdx.x, w = tid >> 6, lane = tid & 63;
    const int quad = lane >> 4, cl = lane & 15;
    const int P0t[5] = {3,0,0,1,2}, P1t[5] = {4,4,1,2,3};
    const int p0 = P0t[n], p1 = P1t[n];
    const int myix = n*NB + idx, f0ix = p0*NB + idx, f1ix = p1*NB + idx;
    const int mt3 = w & 3, half = w >> 2;

    // ---- resident weight fragments (loaded once; fits r4's 128-reg alloc) ----
    half8 w1f[2][4], w2f[2][8], w3f[8];
    #pragma unroll
    for (int i = 0; i < 2; i++) {
        int mt = 2*w + i;
        #pragma unroll
        for (int kk = 0; kk < 4; kk++)
            w1f[i][kk] = *(const half8*)(w1p + (size_t)((n*16 + mt)*4 + kk)*512 + lane*8);
        #pragma unroll
        for (int kk = 0; kk < 8; kk++)
            w2f[i][kk] = *(const half8*)(w2p + (size_t)((n*16 + mt)*8 + kk)*512 + lane*8);
    }
    #pragma unroll
    for (int kk = 0; kk < 8; kk++)
        w3f[kk] = *(const half8*)(w3p + (size_t)((n*4 + mt3)*8 + kk)*512 + lane*8);

    // ---- stage per-node constants ----
    for (int i = tid; i < 1088; i += 512) {
        float v;
        if      (i < 256) v = b1[n*256 + i];
        else if (i < 512) v = b2[n*256 + i - 256];
        else if (i < 576) v = b3[n*64  + i - 512];
        else { int j = i - 576; v = W1[(size_t)(n*130 + (j>>8))*256 + (j & 255)]; }
        cns[i] = v;
    }
    // ---- x_0 into buffer 0 ----
    for (int i = tid; i < 2*BB; i += 512) {
        int pp = i >= BB; int rl = i - pp*BB;
        xls[pp*176 + rl] = x[(size_t)(r0 + rl)*640 + (pp ? p1 : p0)*128 + 0];
    }

    // ---- DMA staging (wave 0 only): 8 rows / instruction ----
    auto stage_dma = [&](int first_row, int R, int buf) {
        int groups = R >> 3;
        for (int q = 0; q < 2*groups; q++) {
            int pp  = q >= groups;
            int grp = q - pp*groups;
            int rl  = first_row + grp*8 + (lane >> 3);
            int g8  = (lane & 7) ^ (rl & 7);            // swizzle in the SOURCE address
            const _Float16* src = Sg
                + ((size_t)((buf*5 + (pp ? p1 : p0))*8192 + r0 + rl))*64 + g8*8;
            DMA16_SC1(src, &Sp[pp*11264 + (first_row + grp*8)*64]);
        }
    };

    for (int t = 0; t < 128; t++) {
        const int xb = (t & 1) * 352;
        // ---- phase 0: wave 0 spins, then issues chunk-0 DMA; one barrier ----
        if (w == 0) {
            if (t > 0 && lane < 2) {
                int* fp = &flags[lane ? f1ix : f0ix];
                while (AGENT_LD(fp) < t) __builtin_amdgcn_s_sleep(1);
            }
            if (t >= 2 && lane == 2) {
                int need = 2*(t-1);
                while (AGENT_LD(&cons[myix]) < need) __builtin_amdgcn_s_sleep(1);
            }
            if (t > 0) stage_dma(0, 64, (t-1) & 1);
        }
        __syncthreads();   // wave0 vmcnt(0) drained -> chunk-0 Sp ready for all

        // ---- chunks of 4 row-tiles: L1 -> L2 -> L3 ----
        #pragma unroll
        for (int c = 0; c < NCH; c++) {
            const int rem_nt = NT - c*4;
            const int cnt = rem_nt < 4 ? rem_nt : 4;
            const int base16 = c*64;

            // stage next chunk (wave 0), or prefetch x_{t+1} (all) on last chunk
            if (c + 1 < NCH) {
                if (w == 0 && t > 0) {
                    int fr = (c+1)*64;
                    int R = BB - fr; if (R > 64) R = 64;
                    stage_dma(fr, R, (t-1) & 1);
                }
            } else if (t < 127) {
                for (int i = tid; i < 2*BB; i += 512) {
                    int pp = i >= BB; int rl = i - pp*BB;
                    xls[((t+1)&1)*352 + pp*176 + rl] =
                        x[(size_t)(r0 + rl)*640 + (pp ? p1 : p0)*128 + (t+1)];
                }
            }

            // ---- L1: i=2 feat-tiles (32 feats/wave), all row-tiles ----
            {
                floatx4 a1[2][4];
                #pragma unroll
                for (int i = 0; i < 2; i++) {
                    int fb = (2*w + i)*16 + quad*4;
                    floatx4 bv = *(const floatx4*)&cns[fb];
                    floatx4 u0 = *(const floatx4*)&cns[576 + fb];
                    floatx4 u1 = *(const floatx4*)&cns[832 + fb];
                    #pragma unroll
                    for (int j = 0; j < 4; j++) if (j < cnt) {
                        int rb = base16 + j*16 + cl;
                        float xa = xls[xb + rb], xc = xls[xb + 176 + rb];
                        a1[i][j] = bv + u0*xa + u1*xc;
                    }
                }
                if (t > 0) {
                    #pragma unroll
                    for (int kk = 0; kk < 4; kk++)
                        #pragma unroll
                        for (int j = 0; j < 4; j++) if (j < cnt) {
                            half8 bf = *(const half8*)&Sp[(kk>>1)*11264 + (base16 + j*16 + cl)*64
                                                          + (((kk&1)*32 + quad*8) ^ SW(cl))];
                            a1[0][j] = __builtin_amdgcn_mfma_f32_16x16x32_f16(w1f[0][kk], bf, a1[0][j], 0,0,0);
                            a1[1][j] = __builtin_amdgcn_mfma_f32_16x16x32_f16(w1f[1][kk], bf, a1[1][j], 0,0,0);
                        }
                }
                #pragma unroll
                for (int i = 0; i < 2; i++) {
                    int fb = (2*w + i)*16 + quad*4;
                    #pragma unroll
                    for (int j = 0; j < 4; j++) if (j < cnt) {
                        int rl = j*16 + cl;
                        half4v pk;
                        #pragma unroll
                        for (int r = 0; r < 4; r++)
                            pk[r] = (_Float16)fmaxf(a1[i][j][r], 0.f);
                        *(half4v*)&H1[rl*256 + (fb ^ SW(cl))] = pk;
                    }
                }
            }
            __syncthreads();   // L1 done; next-chunk DMA (wave0) drained

            // all staging for this step drained -> release producers
            if (c == NCH-1 && t > 0 && tid < 2)
                __hip_atomic_fetch_add(&cons[tid ? f1ix : f0ix], 1,
                                       __ATOMIC_RELAXED, __HIP_MEMORY_SCOPE_AGENT);

            // ---- L2: 256 -> 256, i=2 feat-tiles ----
            {
                floatx4 a2[2][4];
                #pragma unroll
                for (int i = 0; i < 2; i++) {
                    int fb = (2*w + i)*16 + quad*4;
                    floatx4 bv = *(const floatx4*)&cns[256 + fb];
                    #pragma unroll
                    for (int j = 0; j < 4; j++) if (j < cnt) a2[i][j] = bv;
                }
                #pragma unroll
                for (int kk = 0; kk < 8; kk++)
                    #pragma unroll
                    for (int j = 0; j < 4; j++) if (j < cnt) {
                        half8 bf = *(const half8*)&H1[(j*16 + cl)*256 + ((kk*32 + quad*8) ^ SW(cl))];
                        a2[0][j] = __builtin_amdgcn_mfma_f32_16x16x32_f16(w2f[0][kk], bf, a2[0][j], 0,0,0);
                        a2[1][j] = __builtin_amdgcn_mfma_f32_16x16x32_f16(w2f[1][kk], bf, a2[1][j], 0,0,0);
                    }
                #pragma unroll
                for (int i = 0; i < 2; i++) {
                    int fb = (2*w + i)*16 + quad*4;
                    #pragma unroll
                    for (int j = 0; j < 4; j++) if (j < cnt) {
                        int rl = j*16 + cl;
                        half4v pk;
                        #pragma unroll
                        for (int r = 0; r < 4; r++)
                            pk[r] = (_Float16)fmaxf(a2[i][j][r], 0.f);
                        *(half4v*)&H2[rl*256 + (fb ^ SW(cl))] = pk;
                    }
                }
            }
            __syncthreads();   // L2 done

            // ---- L3: 256 -> 64, tanh, state -> global (agent-scope store) ----
            {
                int f3 = mt3*16 + quad*4;
                floatx4 bv = *(const floatx4*)&cns[512 + f3];
                floatx4 a3[2];
                #pragma unroll
                for (int jj = 0; jj < 2; jj++) a3[jj] = bv;
                #pragma unroll
                for (int kk = 0; kk < 8; kk++)
                    #pragma unroll
                    for (int jj = 0; jj < 2; jj++) {
                        int j = half*2 + jj;
                        if (j < cnt) {
                            half8 bf = *(const half8*)&H2[(j*16 + cl)*256 + ((kk*32 + quad*8) ^ SW(cl))];
                            a3[jj] = __builtin_amdgcn_mfma_f32_16x16x32_f16(w3f[kk], bf, a3[jj], 0,0,0);
                        }
                    }
                #pragma unroll
                for (int jj = 0; jj < 2; jj++) {
                    int j = half*2 + jj;
                    if (j < cnt) {
                        int grow = r0 + base16 + j*16 + cl;
                        union { _Float16 hh[4]; u64 q; } pk;
                        #pragma unroll
                        for (int r = 0; r < 4; r++) pk.hh[r] = (_Float16)fast_tanh(a3[jj][r]);
                        AGENT_ST((u64*)(Sg + ((size_t)(((t&1)*5 + n)*8192 + grow))*64 + f3), pk.q);
                    }
                }
            }
            // no barrier: next chunk's L1 writes H1 (disjoint from H2 readers)
        }

        // ---- publish: barrier drains vmcnt(0) for all waves, then flag ----
        __syncthreads();
        if (tid == 0)
            AGENT_ST(&flags[myix], t+1);
    }
}

__global__ __launch_bounds__(512, 2) void scan_kernel(
    const float* __restrict__ x, const float* __restrict__ W1,
    const float* __restrict__ b1, const float* __restrict__ b2, const float* __restrict__ b3,
    const _Float16* __restrict__ w1p, const _Float16* __restrict__ w2p,
    const _Float16* __restrict__ w3p,
    _Float16* __restrict__ Sg, int* flags, int* cons)
{
    extern __shared__ char smem[];
    int b = blockIdx.x;
    int n = b / NB, idx = b % NB;
    int r0 = idx < 2 ? idx*176 : 352 + (idx-2)*160;
    if (idx < 2)
        scan_impl<11>(x, W1, b1, b2, b3, w1p, w2p, w3p, Sg, flags, cons, smem, n, idx, r0);
    else
        scan_impl<10>(x, W1, b1, b2, b3, w1p, w2p, w3p, Sg, flags, cons, smem, n, idx, r0);
}

// ---------------- hpre: relu([x_127, states] @ Wo1 + bo1) ----------------
__global__ __launch_bounds__(512) void hpre_kernel(
    const float* __restrict__ x, const float* __restrict__ Wo1, const float* __restrict__ bo1,
    const _Float16* __restrict__ wo1p, const _Float16* __restrict__ Sg,
    float* __restrict__ hpre)
{
    __shared__ float x5[640];     // [5][128]
    __shared__ float wxo[1280];   // Wo1 rows 0..4
    __shared__ float bo1c[256];
    int tid = threadIdx.x, w = tid >> 6, lane = tid & 63;
    int quad = lane >> 4, cl = lane & 15;
    int r0h = blockIdx.x * 128;

    for (int i = tid; i < 640; i += 512)
        x5[i] = x[(size_t)(r0h + (i & 127))*640 + (i >> 7)*128 + 127];
    for (int i = tid; i < 1280; i += 512) wxo[i] = Wo1[i];
    if (tid < 256) bo1c[tid] = bo1[tid];

    half8 of[2][10];
    #pragma unroll
    for (int i = 0; i < 2; i++) {
        int mt = 2*w + i;
        #pragma unroll
        for (int kk = 0; kk < 10; kk++)
            of[i][kk] = *(const half8*)(wo1p + (size_t)(mt*10 + kk)*512 + lane*8);
    }
    __syncthreads();

    floatx4 acc[2][8];
    #pragma unroll
    for (int i = 0; i < 2; i++) {
        int fb = (2*w + i)*16 + quad*4;
        floatx4 bv = *(const floatx4*)&bo1c[fb];
        #pragma unroll
        for (int nt = 0; nt < 8; nt++) {
            floatx4 a = bv;
            #pragma unroll
            for (int p = 0; p < 5; p++) {
                floatx4 wv = *(const floatx4*)&wxo[p*256 + fb];
                float xv = x5[p*128 + nt*16 + cl];
                a += wv * xv;
            }
            acc[i][nt] = a;
        }
    }
    #pragma unroll
    for (int kk = 0; kk < 10; kk++) {
        int nd = kk >> 1;
        #pragma unroll
        for (int nt = 0; nt < 8; nt++) {
            const _Float16* sp = Sg + ((size_t)((5 + nd)*8192 + r0h + nt*16 + cl))*64
                                    + (kk & 1)*32 + quad*8;   // buf 1 = state(127)
            half8 bf = *(const half8*)sp;
            acc[0][nt] = __builtin_amdgcn_mfma_f32_16x16x32_f16(of[0][kk], bf, acc[0][nt], 0,0,0);
            acc[1][nt] = __builtin_amdgcn_mfma_f32_16x16x32_f16(of[1][kk], bf, acc[1][nt], 0,0,0);
        }
    }
    #pragma unroll
    for (int i = 0; i < 2; i++) {
        int fb = (2*w + i)*16 + quad*4;
        #pragma unroll
        for (int nt = 0; nt < 8; nt++) {
            floatx4 v = acc[i][nt];
            #pragma unroll
            for (int r = 0; r < 4; r++) v[r] = fmaxf(v[r], 0.f);
            *(floatx4*)&hpre[(size_t)(r0h + nt*16 + cl)*256 + fb] = v;
        }
    }
}

// ---------------- BN stats ----------------
__global__ __launch_bounds__(256) void bnstats_kernel(const float* __restrict__ hpre,
                                                      float* __restrict__ sums)
{
    int col = threadIdx.x;
    int r0 = blockIdx.x * 128;
    float s = 0.f, s2 = 0.f;
    for (int r = 0; r < 128; r++) {
        float v = hpre[(size_t)(r0 + r)*256 + col];
        s += v; s2 += v*v;
    }
    atomicAdd(&sums[col], s);
    atomicAdd(&sums[256 + col], s2);
}

// ---------------- normalize + Wo2 + softmax ----------------
__global__ __launch_bounds__(256) void head_kernel(
    const float* __restrict__ hpre, const float* __restrict__ sums,
    const float* __restrict__ gamma, const float* __restrict__ beta,
    const float* __restrict__ Wo2, const float* __restrict__ bo2,
    float* __restrict__ out)
{
    int row  = blockIdx.x * 4 + (threadIdx.x >> 6);
    int lane = threadIdx.x & 63;
    floatx4 h  = *(const floatx4*)&hpre[(size_t)row*256 + lane*4];
    floatx4 sm = *(const floatx4*)&sums[lane*4];
    floatx4 sq = *(const floatx4*)&sums[256 + lane*4];
    floatx4 g  = *(const floatx4*)&gamma[lane*4];
    floatx4 bb = *(const floatx4*)&beta[lane*4];
    float acc[7] = {0.f,0.f,0.f,0.f,0.f,0.f,0.f};
    #pragma unroll
    for (int e = 0; e < 4; e++) {
        float mu  = sm[e] * (1.f/8192.f);
        float var = sq[e] * (1.f/8192.f) - mu*mu;
        float hn  = (h[e] - mu) * rsqrtf(var + 1e-5f) * g[e] + bb[e];
        int colg = lane*4 + e;
        #pragma unroll
        for (int j = 0; j < 7; j++) acc[j] += hn * Wo2[colg*7 + j];
    }
    #pragma unroll
    for (int off = 1; off < 64; off <<= 1) {
        #pragma unroll
        for (int j = 0; j < 7; j++) acc[j] += __shfl_xor(acc[j], off, 64);
    }
    float z[7], m = -1e30f;
    #pragma unroll
    for (int j = 0; j < 7; j++) { z[j] = acc[j] + bo2[j]; m = fmaxf(m, z[j]); }
    float se = 0.f;
    #pragma unroll
    for (int j = 0; j < 7; j++) { z[j] = expf(z[j] - m); se += z[j]; }
    if (lane < 7) out[(size_t)row*7 + lane] = z[lane] / se;
}

extern "C" void kernel_launch(void* const* d_in, const int* in_sizes, int n_in,
                              void* d_out, int out_size, void* d_ws, size_t ws_size,
                              hipStream_t stream)
{
    const float* x    = (const float*)d_in[0];
    const float* W1   = (const float*)d_in[1];
    const float* b1   = (const float*)d_in[2];
    const float* W2   = (const float*)d_in[3];
    const float* b2   = (const float*)d_in[4];
    const float* W3   = (const float*)d_in[5];
    const float* b3   = (const float*)d_in[6];
    const float* Wo1  = (const float*)d_in[7];
    const float* bo1  = (const float*)d_in[8];
    const float* gamma= (const float*)d_in[9];
    const float* beta = (const float*)d_in[10];
    const float* Wo2  = (const float*)d_in[11];
    const float* bo2  = (const float*)d_in[12];
    float* out = (float*)d_out;

    if (ws_size < WS_NEEDED) return;
    char* ws = (char*)d_ws;
    float*     hpre  = (float*)(ws + HPRE_OFF);
    float*     sums  = (float*)(ws + SUM_OFF);
    int*       flags = (int*)(ws + FLAG_OFF);
    int*       cons  = (int*)(ws + CONS_OFF);
    _Float16*  Sg    = (_Float16*)(ws + SG_OFF);
    _Float16*  w1p   = (_Float16*)(ws + PACK_OFF);
    _Float16*  w2p   = w1p + W1P_HALFS;
    _Float16*  w3p   = w2p + W2P_HALFS;
    _Float16*  wo1p  = w3p + W3P_HALFS;

    hipFuncSetAttribute((const void*)scan_kernel,
                        hipFuncAttributeMaxDynamicSharedMemorySize, SMEM_BYTES);

    pack_kernel<<<320, 256, 0, stream>>>(W1, W2, W3, Wo1, w1p, w2p, w3p, wo1p,
                                         sums, flags, cons);
    scan_kernel<<<5*NB, 512, SMEM_BYTES, stream>>>(x, W1, b1, b2, b3,
                                                   w1p, w2p, w3p, Sg, flags, cons);
    hpre_kernel<<<64, 512, 0, stream>>>(x, Wo1, bo1, wo1p, Sg, hpre);
    bnstats_kernel<<<64, 256, 0, stream>>>(hpre, sums);
    head_kernel<<<2048, 256, 0, stream>>>(hpre, sums, gamma, beta, Wo2, bo2, out);
}